// Round 2
// baseline (321.893 us; speedup 1.0000x reference)
//
#include <hip/hip_runtime.h>
#include <hip/hip_bf16.h>

// CrossAttentionFusion: B=4, C=Cs=256, CI=128, H=W=64 -> N=M=4096
// R9 (resubmit; round-1 failure was broker infra, kernel audited clean):
// attn restructured for occupancy: 768-thread blocks (12 waves), grid 512
//  -> 1 block/CU = 12 waves/CU at 3 waves/SIMD (was 8 waves/CU), VGPR budget 170.
//  - main loop BARRIER-FREE: no K LDS staging; K frags read direct from global
//    (same bytes as the old DMA path: kg + s*4096 + cs*512 + lane*8). K/V are
//    L2-resident per XCD (b = (i&7)>>1). chh wave-pairs read identical K addrs
//    in identical order -> L1 dedup.
//  - wave w: kl = w>>1 in [0,6) owns strips s ≡ kl (mod 6) (22/21 strips),
//    chh = w&1 owns 128-ch half of V/O. Fully independent per-wave streams.
//  - Q staged once in LDS (shared by 12 waves; frees 32 VGPR for K-load hoist).
//  - epilogue: l via redu[12], O merged in LDS ostage (kl==0 writes, kl>0
//    ds_add_f32), 4 barriers total, no workspace change.
//  - s_setprio(1) around the pure-reg PV MFMA cluster only.
// prep/proj unchanged from R8.
//
// qk-frag (Q B-op / K A-op), per 32-row group g:
//   addr = g*4096 + (ch>>4)*512 + ((ch>>3)&1)*256 + row*8 + (ch&7)
//   (K rows permuted: row = l32^12 if (l32>>2)&3 in {1,2} -> shuffle-free PV)
// V-frag (PV A-op), per 32-key group g: addr = g*8192 + (ch>>5)*1024
//   + ((key>>4)&1)*512 + ((key>>3)&1)*256 + (ch&31)*8 + (key&7)

typedef __bf16  bf16x8  __attribute__((ext_vector_type(8)));
typedef float   f32x16  __attribute__((ext_vector_type(16)));

#define LOG2E 1.4426950408889634f

union BF8 { __hip_bfloat162 h[4]; bf16x8 v; };
union U4  { unsigned u[4]; bf16x8 v; };

__device__ inline bf16x8 pack8(const float f[8]) {
  BF8 u;
#pragma unroll
  for (int i = 0; i < 4; i++)
    u.h[i] = __float22bfloat162_rn(float2{f[2 * i], f[2 * i + 1]});
  return u.v;
}

// ---------------------------------------------------------------------------
// prep: blocks [0,512): x/z -> X-frag bf16 (LDS transpose, float4 loads);
//       blocks [512,516): W -> W-frag bf16.  (unchanged from R8)
// ---------------------------------------------------------------------------
__global__ __launch_bounds__(256) void prep_kernel(
    const float* __restrict__ x, const float* __restrict__ z,
    const float* __restrict__ Wq, const float* __restrict__ Wk,
    const float* __restrict__ Wv,
    __hip_bfloat16* __restrict__ xf, __hip_bfloat16* __restrict__ zf,
    __hip_bfloat16* __restrict__ wfr)
{
  __shared__ float lds[256 * 68];   // pitch 68: 16B-aligned rows, conflict-free
  const int bi = blockIdx.x;
  const int tid = threadIdx.x;
  if (bi < 512) {
    const int sel = bi >> 8;
    const int b   = (bi >> 6) & 3;
    const int pc  = bi & 63;
    const float* in = sel ? z : x;
    __hip_bfloat16* outp = sel ? zf : xf;
    const size_t ib = (size_t)b * 256 * 4096 + pc * 64;
    const int pix4 = (tid & 15) * 4;
#pragma unroll
    for (int it = 0; it < 16; it++) {
      int ch = it * 16 + (tid >> 4);
      float4 v4 = *(const float4*)&in[ib + (size_t)ch * 4096 + pix4];
      *(float4*)&lds[ch * 68 + pix4] = v4;
    }
    __syncthreads();
    const size_t ob = ((size_t)(b * 128 + pc * 2)) * 8192;
#pragma unroll
    for (int i = 0; i < 8; i++) {
      int c = i * 256 + tid;
      int grp = c >> 10, cs = (c >> 6) & 15, rem = c & 63;
      int hf = rem >> 5, l32 = rem & 31;
      float f[8];
      int chb = cs * 16 + hf * 8;
#pragma unroll
      for (int j = 0; j < 8; j++)
        f[j] = lds[(chb + j) * 68 + grp * 32 + l32];
      *(bf16x8*)(outp + ob + grp * 8192 + cs * 512 + hf * 256 + l32 * 8) =
          pack8(f);
    }
  } else {
    const int base = (bi - 512) * 4096;
#pragma unroll
    for (int i = 0; i < 16; i++) {
      int c = base + i * 256 + tid;
      const float* Ws; __hip_bfloat16* dst; int rc;
      if (c < 4096)      { Ws = Wq; dst = wfr;          rc = c; }
      else if (c < 8192) { Ws = Wk; dst = wfr + 32768;  rc = c - 4096; }
      else               { Ws = Wv; dst = wfr + 65536;  rc = c - 8192; }
      int ot = rc >> 10, cs = (rc >> 6) & 15, rem = rc & 63;
      int hf = rem >> 5, l32 = rem & 31;
      const float* src = Ws + (ot * 32 + l32) * 256 + cs * 16 + hf * 8;
      float f[8];
#pragma unroll
      for (int j = 0; j < 8; j++) f[j] = src[j];
      *(bf16x8*)(dst + ot * 8192 + cs * 512 + hf * 256 + l32 * 8) = pack8(f);
    }
  }
}

// ---------------------------------------------------------------------------
// proj: LDS-free MFMA GEMM, 2-pixel-group interleave (ILP 2), direct stores.
// Grid 512: [0,128) q, [128,256) k, [256,512) v.  (unchanged from R8)
// ---------------------------------------------------------------------------
__global__ __launch_bounds__(256, 2) void proj_mfma(
    const __hip_bfloat16* __restrict__ xf, const __hip_bfloat16* __restrict__ zf,
    const __hip_bfloat16* __restrict__ wfr,
    const float* __restrict__ bq, const float* __restrict__ bk,
    const float* __restrict__ bv,
    __hip_bfloat16* __restrict__ qp, __hip_bfloat16* __restrict__ kp,
    __hip_bfloat16* __restrict__ vp)
{
  const int bi = blockIdx.x;
  int mode, b, pc, h = 0;
  if (bi < 256) { mode = bi >> 7; b = (bi >> 5) & 3; pc = bi & 31; }
  else { int j = bi - 256; mode = 2; b = j >> 6; pc = (j >> 1) & 31; h = j & 1; }
  const int tid = threadIdx.x, w = tid >> 6, lane = tid & 63,
            l32 = lane & 31, half = lane >> 5;

  const __hip_bfloat16* X = (mode == 0) ? xf : zf;
  const int wtile = (mode == 2 ? h * 4 : 0) + w;
  const int wbase = (mode == 0) ? 0 : (mode == 1) ? 32768 : 65536;
  const __hip_bfloat16* wp = wfr + wbase + wtile * 8192 + lane * 8;
  bf16x8 wfg[16];
#pragma unroll
  for (int cs = 0; cs < 16; cs++) wfg[cs] = *(const bf16x8*)(wp + cs * 512);

  const float* bias = (mode == 0) ? bq : (mode == 1) ? bk : bv;
  const int ochb = (mode == 2 ? h * 128 : 0) + w * 32;
  float bb[16];
#pragma unroll
  for (int r = 0; r < 16; r++)
    bb[r] = bias[ochb + (r & 3) + 8 * (r >> 2) + 4 * half];

  const int t4 = (l32 >> 2) & 3;
  const int kperm = (t4 == 1 || t4 == 2) ? (l32 ^ 12) : l32;

#pragma unroll 1
  for (int itp = 0; itp < 2; itp++) {
    const int pg0 = pc * 4 + itp * 2;
    const __hip_bfloat16* xb0 = X + ((size_t)(b * 128 + pg0)) * 8192 + lane * 8;
    const __hip_bfloat16* xb1 = xb0 + 8192;
    f32x16 O0 = {}, O1 = {};
#pragma unroll
    for (int cs = 0; cs < 16; cs++) {
      bf16x8 xr0 = *(const bf16x8*)(xb0 + cs * 512);
      bf16x8 xr1 = *(const bf16x8*)(xb1 + cs * 512);
      O0 = __builtin_amdgcn_mfma_f32_32x32x16_bf16(wfg[cs], xr0, O0, 0, 0, 0);
      O1 = __builtin_amdgcn_mfma_f32_32x32x16_bf16(wfg[cs], xr1, O1, 0, 0, 0);
    }
#pragma unroll
    for (int p = 0; p < 2; p++) {
      const f32x16& O = p ? O1 : O0;
      const int pg = pg0 + p;
      if (mode == 0) {
        __hip_bfloat16* qb = qp + ((size_t)(b * 128 + pg)) * 4096;
#pragma unroll
        for (int r = 0; r < 16; r++) {
          int oc = ochb + (r & 3) + 8 * (r >> 2) + 4 * half;
          qb[(oc >> 4) * 512 + ((oc >> 3) & 1) * 256 + l32 * 8 + (oc & 7)] =
              __float2bfloat16((O[r] + bb[r]) * LOG2E);
        }
      } else if (mode == 1) {
        __hip_bfloat16* kb = kp + ((size_t)(b * 128 + pg)) * 4096;
#pragma unroll
        for (int r = 0; r < 16; r++) {
          int oc = ochb + (r & 3) + 8 * (r >> 2) + 4 * half;
          kb[(oc >> 4) * 512 + ((oc >> 3) & 1) * 256 + kperm * 8 + (oc & 7)] =
              __float2bfloat16(O[r] + bb[r]);
        }
      } else {
        __hip_bfloat16* vb = vp + ((size_t)(b * 128 + pg)) * 8192
            + (h * 4 + w) * 1024 + (l32 >> 4) * 512 + ((l32 >> 3) & 1) * 256
            + (l32 & 7);
#pragma unroll
        for (int r = 0; r < 16; r++) {
          int rr = (r & 3) + 8 * (r >> 2) + 4 * half;
          vb[rr * 8] = __float2bfloat16(O[r] + bb[r]);
        }
      }
    }
  }
}

// ---------------------------------------------------------------------------
// attn R9: block (b, 32 q), 768 threads = 12 waves, barrier-free main loop.
// wave w: kl = w>>1 owns strips s ≡ kl (mod 6); chh = w&1 owns 128-ch half.
// K/V frags direct from global (L2-resident per XCD; chh pair dedups via L1).
// Q staged once in LDS. Epilogue: redu + ostage merge (write + ds_add_f32).
// ---------------------------------------------------------------------------
struct AttnSmem {
  __hip_bfloat16 qlds[4096];     // 8 KiB, Q frags shared by all 12 waves
  float ost[256][33];            // 33.8 KiB merge buffer [ch][q], pad 33
  float redu[12][32];
  float rinv[32];
};

__global__ __launch_bounds__(768, 3) void attn_kernel(
    const __hip_bfloat16* __restrict__ qv, const __hip_bfloat16* __restrict__ kv,
    const __hip_bfloat16* __restrict__ vv,
    const float* __restrict__ x_main, const float* __restrict__ gammap,
    float* __restrict__ out)
{
  __shared__ AttnSmem sm;
  const int i  = blockIdx.x;           // 512 blocks
  const int b  = (i & 7) >> 1;         // XCD-pair -> batch (K+V L2-resident)
  const int qt = ((i >> 3) << 1) | (i & 1);
  const int n0 = qt * 32;
  const int tid  = threadIdx.x;
  const int w    = tid >> 6, lane = tid & 63, l32 = lane & 31, hb = lane >> 5;
  const int kl   = w >> 1, chh = w & 1;

  // Q -> LDS once (all waves share the same 32 q rows)
  if (tid < 512)
    *(bf16x8*)(sm.qlds + tid * 8) =
        *(const bf16x8*)(qv + ((size_t)(b * 128 + qt)) * 4096 + tid * 8);
  __syncthreads();

  const __hip_bfloat16* kg = kv + (size_t)(b * 128) * 4096;
  const __hip_bfloat16* vg = vv + (size_t)(b * 128) * 8192;
  const __hip_bfloat16* qb = sm.qlds + lane * 8;

  f32x16 Oacc[4];   // O^T: 128 ch (chh half) x 32 q, partial over kl strips
#pragma unroll
  for (int c = 0; c < 4; c++)
#pragma unroll
    for (int r = 0; r < 16; r++) Oacc[c][r] = 0.f;

  float l_lane = 0.f;

  // strip list: s = kl + 6*kj, kj in [0,L); L = 22 for kl<2 else 21 (128 total)
  const int L = (kl < 2) ? 22 : 21;
  int kj = (qt * 3 + kl) % L;          // stagger across blocks; chh pair in sync

#pragma unroll 1
  for (int j = 0; j < L; ++j) {
    const int s = kl + 6 * kj;
    ++kj; if (kj == L) kj = 0;

    const __hip_bfloat16* kb = kg + (size_t)s * 4096 + lane * 8;
    const __hip_bfloat16* vb = vg + (size_t)s * 8192 + chh * 4096 + lane * 8;

    // V frags hoisted (consumed after softmax -> latency covered)
    bf16x8 Vc[8];
#pragma unroll
    for (int c = 0; c < 4; c++) {
      Vc[2 * c]     = *(const bf16x8*)(vb + c * 1024);
      Vc[2 * c + 1] = *(const bf16x8*)(vb + c * 1024 + 512);
    }

    // S^T = K Q  (K frags streamed from global, Q from LDS)
    f32x16 S = {};
#pragma unroll
    for (int cs = 0; cs < 8; cs++) {
      bf16x8 kf = *(const bf16x8*)(kb + cs * 512);
      bf16x8 qf = *(const bf16x8*)(qb + cs * 512);
      S = __builtin_amdgcn_mfma_f32_32x32x16_bf16(kf, qf, S, 0, 0, 0);
    }

    // P = exp2(S - 64), pack bf16 (shuffle-free via K row perm in proj)
    unsigned p2[8];
    float lsub = 0.f;
#pragma unroll
    for (int i2 = 0; i2 < 8; i2++) {
      float a = exp2f(S[2 * i2]     - 64.0f);
      float c = exp2f(S[2 * i2 + 1] - 64.0f);
      lsub += a + c;
      union { __hip_bfloat162 h; unsigned u; } cv;
      cv.h = __float22bfloat162_rn(float2{a, c});
      p2[i2] = cv.u;
    }
    l_lane += lsub;
    U4 f0, f1;
    f0.u[0] = p2[0]; f0.u[1] = p2[1]; f0.u[2] = p2[2]; f0.u[3] = p2[3];
    f1.u[0] = p2[4]; f1.u[1] = p2[5]; f1.u[2] = p2[6]; f1.u[3] = p2[7];
    const bf16x8 pf0 = f0.v, pf1 = f1.v;

    // PV: pure-register MFMA cluster
    __builtin_amdgcn_s_setprio(1);
#pragma unroll
    for (int c = 0; c < 4; c++) {
      Oacc[c] = __builtin_amdgcn_mfma_f32_32x32x16_bf16(Vc[2 * c],     pf0, Oacc[c], 0, 0, 0);
      Oacc[c] = __builtin_amdgcn_mfma_f32_32x32x16_bf16(Vc[2 * c + 1], pf1, Oacc[c], 0, 0, 0);
    }
    __builtin_amdgcn_s_setprio(0);
  }

  // ---- epilogue: publish l, merge 6 kl-partials in LDS, writeout ----
  float lfull = l_lane + __shfl_xor(l_lane, 32);
  if (lane < 32) sm.redu[w][l32] = lfull;
  __syncthreads();

  if (kl == 0) {
#pragma unroll
    for (int c = 0; c < 4; c++)
#pragma unroll
      for (int r = 0; r < 16; r++) {
        int ch = (chh * 4 + c) * 32 + (r & 3) + 8 * (r >> 2) + 4 * hb;
        sm.ost[ch][l32] = Oacc[c][r];
      }
  }
  if (tid < 32) {
    float t = sm.redu[0][tid] + sm.redu[2][tid] + sm.redu[4][tid]
            + sm.redu[6][tid] + sm.redu[8][tid] + sm.redu[10][tid];
    sm.rinv[tid] = 1.0f / t;
  }
  __syncthreads();
  if (kl != 0) {
#pragma unroll
    for (int c = 0; c < 4; c++)
#pragma unroll
      for (int r = 0; r < 16; r++) {
        int ch = (chh * 4 + c) * 32 + (r & 3) + 8 * (r >> 2) + 4 * hb;
        atomicAdd(&sm.ost[ch][l32], Oacc[c][r]);   // ds_add_f32, 5-way
      }
  }
  __syncthreads();

  const float gmm = gammap[0];
#pragma unroll 1
  for (int idx = tid; idx < 8192; idx += 768) {
    int ch = idx >> 5, pix = idx & 31;
    size_t g = ((size_t)(b * 256 + ch)) * 4096 + n0 + pix;
    out[g] = gmm * sm.ost[ch][pix] * sm.rinv[pix] + x_main[g];
  }
}

// ---------------------------------------------------------------------------
extern "C" void kernel_launch(void* const* d_in, const int* in_sizes, int n_in,
                              void* d_out, int out_size, void* d_ws, size_t ws_size,
                              hipStream_t stream) {
  (void)in_sizes; (void)n_in; (void)out_size; (void)ws_size;
  const float* x  = (const float*)d_in[0];
  const float* z  = (const float*)d_in[1];
  const float* Wq = (const float*)d_in[2];
  const float* bq = (const float*)d_in[3];
  const float* Wk = (const float*)d_in[4];
  const float* bk = (const float*)d_in[5];
  const float* Wv = (const float*)d_in[6];
  const float* bv = (const float*)d_in[7];
  const float* gm = (const float*)d_in[8];
  float* out = (float*)d_out;

  char* ws = (char*)d_ws;
  const size_t MB = 1024 * 1024;
  __hip_bfloat16* qp  = (__hip_bfloat16*)(ws);             // 4 MiB
  __hip_bfloat16* kp  = (__hip_bfloat16*)(ws + 4 * MB);    // 4 MiB
  __hip_bfloat16* vp  = (__hip_bfloat16*)(ws + 8 * MB);    // 8 MiB
  __hip_bfloat16* xfp = (__hip_bfloat16*)(ws + 16 * MB);   // 8 MiB
  __hip_bfloat16* zfp = (__hip_bfloat16*)(ws + 24 * MB);   // 8 MiB
  __hip_bfloat16* wfp = (__hip_bfloat16*)(ws + 32 * MB);   // 256 KiB

  prep_kernel<<<516, 256, 0, stream>>>(x, z, Wq, Wk, Wv, xfp, zfp, wfp);
  proj_mfma  <<<512, 256, 0, stream>>>(xfp, zfp, wfp, bq, bk, bv, qp, kp, vp);
  attn_kernel<<<512, 768, 0, stream>>>(qp, kp, vp, x, gm, out);
}

// Round 3
// 240.202 us; speedup vs baseline: 1.3401x; 1.3401x over previous
//
#include <hip/hip_runtime.h>
#include <hip/hip_bf16.h>

// CrossAttentionFusion: B=4, C=Cs=256, CI=128, H=W=64 -> N=M=4096
// R10 = R8 structure (best measured: 113us attn) + chh-pair QK/softmax dedup:
//  - R9 post-mortem: direct-global K streaming at 3 waves/SIMD starved the
//    register allocator -> serialized loads -> 2x regression. Reverted.
//  - In R8, waves (kh,chh=0) and (kh,chh=1) computed IDENTICAL S^T and exp
//    (S depends only on kh; epilogue uses only chh=0's l). R10: chh=0 computes
//    QK+exp+pack, publishes P frags to LDS (32B/lane, lane-identical
//    write/read -> no transpose, lane*16B stride = conflict-free); barrier;
//    chh=1 reads P; both run PV. -25% MFMA issue, -50% exp VALU.
//  - K DMA staging reassigned to chh=1 waves (8 dma16 each) so they issue
//    work during chh=0's QK phase. 2 barriers/tile (was 1).
//  - V loads at tile start (both chh), tile-order stagger t0 = qt & 63 kept.
// prep/proj unchanged from R8.
//
// qk-frag (Q B-op / K A-op), per 32-row group g:
//   addr = g*4096 + (ch>>4)*512 + ((ch>>3)&1)*256 + row*8 + (ch&7)
//   (K rows permuted: row = l32^12 if (l32>>2)&3 in {1,2} -> shuffle-free PV)
// V-frag (PV A-op), per 32-key group g: addr = g*8192 + (ch>>5)*1024
//   + ((key>>4)&1)*512 + ((key>>3)&1)*256 + (ch&31)*8 + (key&7)

typedef __bf16  bf16x8  __attribute__((ext_vector_type(8)));
typedef float   f32x16  __attribute__((ext_vector_type(16)));

#define LOG2E 1.4426950408889634f

union BF8 { __hip_bfloat162 h[4]; bf16x8 v; };
union U4  { unsigned u[4]; bf16x8 v; };

__device__ inline bf16x8 pack8(const float f[8]) {
  BF8 u;
#pragma unroll
  for (int i = 0; i < 4; i++)
    u.h[i] = __float22bfloat162_rn(float2{f[2 * i], f[2 * i + 1]});
  return u.v;
}

__device__ inline void dma16(const void* g, void* l) {
  __builtin_amdgcn_global_load_lds(
      (const __attribute__((address_space(1))) unsigned int*)g,
      (__attribute__((address_space(3))) unsigned int*)l, 16, 0, 0);
}

// ---------------------------------------------------------------------------
// prep: blocks [0,512): x/z -> X-frag bf16 (LDS transpose, float4 loads);
//       blocks [512,516): W -> W-frag bf16.  (unchanged from R8)
// ---------------------------------------------------------------------------
__global__ __launch_bounds__(256) void prep_kernel(
    const float* __restrict__ x, const float* __restrict__ z,
    const float* __restrict__ Wq, const float* __restrict__ Wk,
    const float* __restrict__ Wv,
    __hip_bfloat16* __restrict__ xf, __hip_bfloat16* __restrict__ zf,
    __hip_bfloat16* __restrict__ wfr)
{
  __shared__ float lds[256 * 68];   // pitch 68: 16B-aligned rows, conflict-free
  const int bi = blockIdx.x;
  const int tid = threadIdx.x;
  if (bi < 512) {
    const int sel = bi >> 8;
    const int b   = (bi >> 6) & 3;
    const int pc  = bi & 63;
    const float* in = sel ? z : x;
    __hip_bfloat16* outp = sel ? zf : xf;
    const size_t ib = (size_t)b * 256 * 4096 + pc * 64;
    const int pix4 = (tid & 15) * 4;
#pragma unroll
    for (int it = 0; it < 16; it++) {
      int ch = it * 16 + (tid >> 4);
      float4 v4 = *(const float4*)&in[ib + (size_t)ch * 4096 + pix4];
      *(float4*)&lds[ch * 68 + pix4] = v4;
    }
    __syncthreads();
    const size_t ob = ((size_t)(b * 128 + pc * 2)) * 8192;
#pragma unroll
    for (int i = 0; i < 8; i++) {
      int c = i * 256 + tid;
      int grp = c >> 10, cs = (c >> 6) & 15, rem = c & 63;
      int hf = rem >> 5, l32 = rem & 31;
      float f[8];
      int chb = cs * 16 + hf * 8;
#pragma unroll
      for (int j = 0; j < 8; j++)
        f[j] = lds[(chb + j) * 68 + grp * 32 + l32];
      *(bf16x8*)(outp + ob + grp * 8192 + cs * 512 + hf * 256 + l32 * 8) =
          pack8(f);
    }
  } else {
    const int base = (bi - 512) * 4096;
#pragma unroll
    for (int i = 0; i < 16; i++) {
      int c = base + i * 256 + tid;
      const float* Ws; __hip_bfloat16* dst; int rc;
      if (c < 4096)      { Ws = Wq; dst = wfr;          rc = c; }
      else if (c < 8192) { Ws = Wk; dst = wfr + 32768;  rc = c - 4096; }
      else               { Ws = Wv; dst = wfr + 65536;  rc = c - 8192; }
      int ot = rc >> 10, cs = (rc >> 6) & 15, rem = rc & 63;
      int hf = rem >> 5, l32 = rem & 31;
      const float* src = Ws + (ot * 32 + l32) * 256 + cs * 16 + hf * 8;
      float f[8];
#pragma unroll
      for (int j = 0; j < 8; j++) f[j] = src[j];
      *(bf16x8*)(dst + ot * 8192 + cs * 512 + hf * 256 + l32 * 8) = pack8(f);
    }
  }
}

// ---------------------------------------------------------------------------
// proj: LDS-free MFMA GEMM, 2-pixel-group interleave (ILP 2), direct stores.
// Grid 512: [0,128) q, [128,256) k, [256,512) v.  (unchanged from R8)
// ---------------------------------------------------------------------------
__global__ __launch_bounds__(256, 2) void proj_mfma(
    const __hip_bfloat16* __restrict__ xf, const __hip_bfloat16* __restrict__ zf,
    const __hip_bfloat16* __restrict__ wfr,
    const float* __restrict__ bq, const float* __restrict__ bk,
    const float* __restrict__ bv,
    __hip_bfloat16* __restrict__ qp, __hip_bfloat16* __restrict__ kp,
    __hip_bfloat16* __restrict__ vp)
{
  const int bi = blockIdx.x;
  int mode, b, pc, h = 0;
  if (bi < 256) { mode = bi >> 7; b = (bi >> 5) & 3; pc = bi & 31; }
  else { int j = bi - 256; mode = 2; b = j >> 6; pc = (j >> 1) & 31; h = j & 1; }
  const int tid = threadIdx.x, w = tid >> 6, lane = tid & 63,
            l32 = lane & 31, half = lane >> 5;

  const __hip_bfloat16* X = (mode == 0) ? xf : zf;
  const int wtile = (mode == 2 ? h * 4 : 0) + w;
  const int wbase = (mode == 0) ? 0 : (mode == 1) ? 32768 : 65536;
  const __hip_bfloat16* wp = wfr + wbase + wtile * 8192 + lane * 8;
  bf16x8 wfg[16];
#pragma unroll
  for (int cs = 0; cs < 16; cs++) wfg[cs] = *(const bf16x8*)(wp + cs * 512);

  const float* bias = (mode == 0) ? bq : (mode == 1) ? bk : bv;
  const int ochb = (mode == 2 ? h * 128 : 0) + w * 32;
  float bb[16];
#pragma unroll
  for (int r = 0; r < 16; r++)
    bb[r] = bias[ochb + (r & 3) + 8 * (r >> 2) + 4 * half];

  const int t4 = (l32 >> 2) & 3;
  const int kperm = (t4 == 1 || t4 == 2) ? (l32 ^ 12) : l32;

#pragma unroll 1
  for (int itp = 0; itp < 2; itp++) {
    const int pg0 = pc * 4 + itp * 2;
    const __hip_bfloat16* xb0 = X + ((size_t)(b * 128 + pg0)) * 8192 + lane * 8;
    const __hip_bfloat16* xb1 = xb0 + 8192;
    f32x16 O0 = {}, O1 = {};
#pragma unroll
    for (int cs = 0; cs < 16; cs++) {
      bf16x8 xr0 = *(const bf16x8*)(xb0 + cs * 512);
      bf16x8 xr1 = *(const bf16x8*)(xb1 + cs * 512);
      O0 = __builtin_amdgcn_mfma_f32_32x32x16_bf16(wfg[cs], xr0, O0, 0, 0, 0);
      O1 = __builtin_amdgcn_mfma_f32_32x32x16_bf16(wfg[cs], xr1, O1, 0, 0, 0);
    }
#pragma unroll
    for (int p = 0; p < 2; p++) {
      const f32x16& O = p ? O1 : O0;
      const int pg = pg0 + p;
      if (mode == 0) {
        __hip_bfloat16* qb = qp + ((size_t)(b * 128 + pg)) * 4096;
#pragma unroll
        for (int r = 0; r < 16; r++) {
          int oc = ochb + (r & 3) + 8 * (r >> 2) + 4 * half;
          qb[(oc >> 4) * 512 + ((oc >> 3) & 1) * 256 + l32 * 8 + (oc & 7)] =
              __float2bfloat16((O[r] + bb[r]) * LOG2E);
        }
      } else if (mode == 1) {
        __hip_bfloat16* kb = kp + ((size_t)(b * 128 + pg)) * 4096;
#pragma unroll
        for (int r = 0; r < 16; r++) {
          int oc = ochb + (r & 3) + 8 * (r >> 2) + 4 * half;
          kb[(oc >> 4) * 512 + ((oc >> 3) & 1) * 256 + kperm * 8 + (oc & 7)] =
              __float2bfloat16(O[r] + bb[r]);
        }
      } else {
        __hip_bfloat16* vb = vp + ((size_t)(b * 128 + pg)) * 8192
            + (h * 4 + w) * 1024 + (l32 >> 4) * 512 + ((l32 >> 3) & 1) * 256
            + (l32 & 7);
#pragma unroll
        for (int r = 0; r < 16; r++) {
          int rr = (r & 3) + 8 * (r >> 2) + 4 * half;
          vb[rr * 8] = __float2bfloat16(O[r] + bb[r]);
        }
      }
    }
  }
}

// ---------------------------------------------------------------------------
// attn R10: R8 structure + chh-pair QK/softmax dedup via LDS P-publish.
// Block (b, 32 q), 4 waves = (kh, chh). K DMA+LDS dbuf (chh=1 waves stage);
// chh=0 computes S/exp/P and publishes; chh=1 reads P; both run PV.
// 2 barriers/tile. V direct global frag loads; 64 tiles staggered.
// ---------------------------------------------------------------------------
struct AttnSmem {
  union {
    struct {
      __hip_bfloat16 kbuf[2][8192];   // 2 x 16 KiB double buffer
      __hip_bfloat16 plds[2][2048];   // [kh] 2 frags x 64 lanes x 16B = 4 KiB ea
    } m;
    float ostage[256][33];            // epilogue [ch][q], pad 33
  } u;
  float redu[4][32];
  float rinv[32];
};

__global__ __launch_bounds__(256, 3) void attn_kernel(
    const __hip_bfloat16* __restrict__ qv, const __hip_bfloat16* __restrict__ kv,
    const __hip_bfloat16* __restrict__ vv,
    const float* __restrict__ x_main, const float* __restrict__ gammap,
    float* __restrict__ out)
{
  __shared__ AttnSmem sm;
  const int i  = blockIdx.x;           // 512 blocks
  const int b  = (i & 7) >> 1;         // XCD-pair -> batch (K+V L2-resident)
  const int qt = ((i >> 3) << 1) | (i & 1);
  const int n0 = qt * 32;
  const int tid  = threadIdx.x;
  const int w    = tid >> 6, lane = tid & 63, l32 = lane & 31;
  const int kh   = w >> 1, chh = w & 1;
  const int t0   = qt & 63;            // stagger: de-correlate block streams

  // Q B-fragments: only QK waves (chh=0) need them
  bf16x8 qf[8];
  if (chh == 0) {
    const __hip_bfloat16* qb = qv + ((size_t)(b * 128 + qt)) * 4096 + lane * 8;
#pragma unroll
    for (int cs = 0; cs < 8; cs++) qf[cs] = *(const bf16x8*)(qb + cs * 512);
  }

  const __hip_bfloat16* kg = kv + (size_t)(b * 128) * 4096;
  const __hip_bfloat16* vg = vv + (size_t)(b * 128) * 8192;

  // chh=1 waves own K staging (8 dma16 each, 16 KiB tile total); issued while
  // chh=0 runs QK+exp of the current tile.
  auto stage = [&](int ta, int par) {
    if (chh == 0) return;
    __hip_bfloat16* kd = sm.u.m.kbuf[par];
    const __hip_bfloat16* ksrc = kg + (size_t)ta * 8192 + lane * 8;
#pragma unroll
    for (int c = 0; c < 8; c++) {
      int ck = kh * 8 + c;
      dma16(ksrc + ck * 512, kd + ck * 512 + lane * 8);
    }
  };

  f32x16 Oacc[4];   // O^T: 128 ch (chh half) x 32 q, partial over kh keys
#pragma unroll
  for (int c = 0; c < 4; c++)
#pragma unroll
    for (int r = 0; r < 16; r++) Oacc[c][r] = 0.f;

  float l_lane = 0.f;

  // one tile: V loads (all waves); chh=0: S^T = K Q from LDS-K, P = exp2(S-64),
  // publish P frags; barrier; chh=1 reads P; both: PV.
  auto body = [&](int par, int ta) {
    const __hip_bfloat16* vb = vg + (size_t)(ta * 2 + kh) * 8192
                             + chh * 4096 + lane * 8;
    bf16x8 Vc[8];
#pragma unroll
    for (int c = 0; c < 4; c++) {
      Vc[2 * c]     = *(const bf16x8*)(vb + c * 1024);
      Vc[2 * c + 1] = *(const bf16x8*)(vb + c * 1024 + 512);
    }
    bf16x8 pf0, pf1;
    if (chh == 0) {
      const __hip_bfloat16* kbase = sm.u.m.kbuf[par] + kh * 4096 + lane * 8;
      f32x16 S = {};
#pragma unroll
      for (int cs = 0; cs < 8; cs++) {
        bf16x8 kf = *(const bf16x8*)(kbase + cs * 512);
        S = __builtin_amdgcn_mfma_f32_32x32x16_bf16(kf, qf[cs], S, 0, 0, 0);
      }
      unsigned p2[8];
      float lsub = 0.f;
#pragma unroll
      for (int i2 = 0; i2 < 8; i2++) {
        float a = exp2f(S[2 * i2]     - 64.0f);
        float c = exp2f(S[2 * i2 + 1] - 64.0f);
        lsub += a + c;
        union { __hip_bfloat162 h; unsigned u; } cv;
        cv.h = __float22bfloat162_rn(float2{a, c});
        p2[i2] = cv.u;
      }
      l_lane += lsub;
      U4 f0, f1;
      f0.u[0] = p2[0]; f0.u[1] = p2[1]; f0.u[2] = p2[2]; f0.u[3] = p2[3];
      f1.u[0] = p2[4]; f1.u[1] = p2[5]; f1.u[2] = p2[6]; f1.u[3] = p2[7];
      pf0 = f0.v; pf1 = f1.v;
      *(bf16x8*)(sm.u.m.plds[kh] + lane * 8)        = pf0;
      *(bf16x8*)(sm.u.m.plds[kh] + 1024 + lane * 8) = pf1;
    }
    __syncthreads();                    // barrier B: P published (lgkmcnt(0))
    if (chh == 1) {
      pf0 = *(const bf16x8*)(sm.u.m.plds[kh] + lane * 8);
      pf1 = *(const bf16x8*)(sm.u.m.plds[kh] + 1024 + lane * 8);
    }
#pragma unroll
    for (int c = 0; c < 4; c++) {
      Oacc[c] = __builtin_amdgcn_mfma_f32_32x32x16_bf16(Vc[2 * c],     pf0, Oacc[c], 0, 0, 0);
      Oacc[c] = __builtin_amdgcn_mfma_f32_32x32x16_bf16(Vc[2 * c + 1], pf1, Oacc[c], 0, 0, 0);
    }
  };

  // ---- pipelined main loop, 2 barriers/tile, staggered tile order ----
  stage(t0, 0);
  __syncthreads();                 // tile t0 landed
  stage((t0 + 1) & 63, 1);
  body(0, t0);
#pragma unroll 1
  for (int lt = 1; lt < 64; ++lt) {
    __syncthreads();               // drains stage issued one body ago
    if (lt < 63) stage((lt + 1 + t0) & 63, (lt + 1) & 1);
    body(lt & 1, (lt + t0) & 63);
  }

  // ---- epilogue: publish l, kh-merge via ostage (ch rows), writeout ----
  float lfull = l_lane + __shfl_xor(l_lane, 32);
  if (lane < 32) sm.redu[w][l32] = lfull;
  __syncthreads();                 // kbuf/plds reads done; redu published
  const int hb = lane >> 5;
  if (kh == 0) {
#pragma unroll
    for (int c = 0; c < 4; c++) {
#pragma unroll
      for (int r = 0; r < 16; r++) {
        int ch = (chh * 4 + c) * 32 + (r & 3) + 8 * (r >> 2) + 4 * hb;
        sm.u.ostage[ch][l32] = Oacc[c][r];
      }
    }
  }
  if (tid < 32) sm.rinv[tid] = 1.0f / (sm.redu[0][tid] + sm.redu[2][tid]);
  __syncthreads();
  if (kh == 1) {
#pragma unroll
    for (int c = 0; c < 4; c++) {
#pragma unroll
      for (int r = 0; r < 16; r++) {
        int ch = (chh * 4 + c) * 32 + (r & 3) + 8 * (r >> 2) + 4 * hb;
        sm.u.ostage[ch][l32] += Oacc[c][r];
      }
    }
  }
  __syncthreads();

  const float gmm = gammap[0];
  const int pix = tid & 31;
  const float ri = sm.rinv[pix];
#pragma unroll
  for (int j = 0; j < 32; ++j) {
    int ch = (tid >> 5) * 32 + j;
    size_t g = ((size_t)(b * 256 + ch)) * 4096 + n0 + pix;
    out[g] = gmm * sm.u.ostage[ch][pix] * ri + x_main[g];
  }
}

// ---------------------------------------------------------------------------
extern "C" void kernel_launch(void* const* d_in, const int* in_sizes, int n_in,
                              void* d_out, int out_size, void* d_ws, size_t ws_size,
                              hipStream_t stream) {
  (void)in_sizes; (void)n_in; (void)out_size; (void)ws_size;
  const float* x  = (const float*)d_in[0];
  const float* z  = (const float*)d_in[1];
  const float* Wq = (const float*)d_in[2];
  const float* bq = (const float*)d_in[3];
  const float* Wk = (const float*)d_in[4];
  const float* bk = (const float*)d_in[5];
  const float* Wv = (const float*)d_in[6];
  const float* bv = (const float*)d_in[7];
  const float* gm = (const float*)d_in[8];
  float* out = (float*)d_out;

  char* ws = (char*)d_ws;
  const size_t MB = 1024 * 1024;
  __hip_bfloat16* qp  = (__hip_bfloat16*)(ws);             // 4 MiB
  __hip_bfloat16* kp  = (__hip_bfloat16*)(ws + 4 * MB);    // 4 MiB
  __hip_bfloat16* vp  = (__hip_bfloat16*)(ws + 8 * MB);    // 8 MiB
  __hip_bfloat16* xfp = (__hip_bfloat16*)(ws + 16 * MB);   // 8 MiB
  __hip_bfloat16* zfp = (__hip_bfloat16*)(ws + 24 * MB);   // 8 MiB
  __hip_bfloat16* wfp = (__hip_bfloat16*)(ws + 32 * MB);   // 256 KiB

  prep_kernel<<<516, 256, 0, stream>>>(x, z, Wq, Wk, Wv, xfp, zfp, wfp);
  proj_mfma  <<<512, 256, 0, stream>>>(xfp, zfp, wfp, bq, bk, bv, qp, kp, vp);
  attn_kernel<<<512, 256, 0, stream>>>(qp, kp, vp, x, gm, out);
}

// Round 5
// 219.680 us; speedup vs baseline: 1.4653x; 1.0934x over previous
//
#include <hip/hip_runtime.h>
#include <hip/hip_bf16.h>

// CrossAttentionFusion: B=4, C=Cs=256, CI=128, H=W=64 -> N=M=4096
// R11 (resubmit; round-4 failure was broker infra, kernel audited clean):
// R8 body, stream-count attack:
//  - R9 lesson: direct-global K at 12 waves/block starves regs -> serialized.
//  - R10 lesson: P-dedup via LDS adds 6.3M bank conflicts + barrier lockstep.
//    => R8's limit is 2 independent block-streams/CU on a serial tile chain.
//  - attn: split-K. grid 1024, kt2 halves of the key range, R8 body UNCHANGED
//    (same regs/LDS -> 3 blocks/CU, half serial chain). Blocks write
//    unnormalized O-partials (f32) + l-partials; merge_kernel normalizes,
//    applies gamma and residual. Host hedges on ws_size: falls back to the
//    exact R8 single-pass attn (attn_kernel<0>) if workspace is small.
//  - proj: grid 512 -> 1024 (one O0/O1 pixel-group pair per block, ILP-2
//    kept), launch_bounds(256,3) -> 3 blocks/CU, half serial chain.
//  - prep unchanged.
//
// qk-frag (Q B-op / K A-op), per 32-row group g:
//   addr = g*4096 + (ch>>4)*512 + ((ch>>3)&1)*256 + row*8 + (ch&7)
//   (K rows permuted: row = l32^12 if (l32>>2)&3 in {1,2} -> shuffle-free PV)
// V-frag (PV A-op), per 32-key group g: addr = g*8192 + (ch>>5)*1024
//   + ((key>>4)&1)*512 + ((key>>3)&1)*256 + (ch&31)*8 + (key&7)

typedef __bf16  bf16x8  __attribute__((ext_vector_type(8)));
typedef float   f32x16  __attribute__((ext_vector_type(16)));

#define LOG2E 1.4426950408889634f

union BF8 { __hip_bfloat162 h[4]; bf16x8 v; };
union U4  { unsigned u[4]; bf16x8 v; };

__device__ inline bf16x8 pack8(const float f[8]) {
  BF8 u;
#pragma unroll
  for (int i = 0; i < 4; i++)
    u.h[i] = __float22bfloat162_rn(float2{f[2 * i], f[2 * i + 1]});
  return u.v;
}

__device__ inline void dma16(const void* g, void* l) {
  __builtin_amdgcn_global_load_lds(
      (const __attribute__((address_space(1))) unsigned int*)g,
      (__attribute__((address_space(3))) unsigned int*)l, 16, 0, 0);
}

// ---------------------------------------------------------------------------
// prep: blocks [0,512): x/z -> X-frag bf16 (LDS transpose, float4 loads);
//       blocks [512,516): W -> W-frag bf16.  (unchanged from R8)
// ---------------------------------------------------------------------------
__global__ __launch_bounds__(256) void prep_kernel(
    const float* __restrict__ x, const float* __restrict__ z,
    const float* __restrict__ Wq, const float* __restrict__ Wk,
    const float* __restrict__ Wv,
    __hip_bfloat16* __restrict__ xf, __hip_bfloat16* __restrict__ zf,
    __hip_bfloat16* __restrict__ wfr)
{
  __shared__ float lds[256 * 68];   // pitch 68: 16B-aligned rows, conflict-free
  const int bi = blockIdx.x;
  const int tid = threadIdx.x;
  if (bi < 512) {
    const int sel = bi >> 8;
    const int b   = (bi >> 6) & 3;
    const int pc  = bi & 63;
    const float* in = sel ? z : x;
    __hip_bfloat16* outp = sel ? zf : xf;
    const size_t ib = (size_t)b * 256 * 4096 + pc * 64;
    const int pix4 = (tid & 15) * 4;
#pragma unroll
    for (int it = 0; it < 16; it++) {
      int ch = it * 16 + (tid >> 4);
      float4 v4 = *(const float4*)&in[ib + (size_t)ch * 4096 + pix4];
      *(float4*)&lds[ch * 68 + pix4] = v4;
    }
    __syncthreads();
    const size_t ob = ((size_t)(b * 128 + pc * 2)) * 8192;
#pragma unroll
    for (int i = 0; i < 8; i++) {
      int c = i * 256 + tid;
      int grp = c >> 10, cs = (c >> 6) & 15, rem = c & 63;
      int hf = rem >> 5, l32 = rem & 31;
      float f[8];
      int chb = cs * 16 + hf * 8;
#pragma unroll
      for (int j = 0; j < 8; j++)
        f[j] = lds[(chb + j) * 68 + grp * 32 + l32];
      *(bf16x8*)(outp + ob + grp * 8192 + cs * 512 + hf * 256 + l32 * 8) =
          pack8(f);
    }
  } else {
    const int base = (bi - 512) * 4096;
#pragma unroll
    for (int i = 0; i < 16; i++) {
      int c = base + i * 256 + tid;
      const float* Ws; __hip_bfloat16* dst; int rc;
      if (c < 4096)      { Ws = Wq; dst = wfr;          rc = c; }
      else if (c < 8192) { Ws = Wk; dst = wfr + 32768;  rc = c - 4096; }
      else               { Ws = Wv; dst = wfr + 65536;  rc = c - 8192; }
      int ot = rc >> 10, cs = (rc >> 6) & 15, rem = rc & 63;
      int hf = rem >> 5, l32 = rem & 31;
      const float* src = Ws + (ot * 32 + l32) * 256 + cs * 16 + hf * 8;
      float f[8];
#pragma unroll
      for (int j = 0; j < 8; j++) f[j] = src[j];
      *(bf16x8*)(dst + ot * 8192 + cs * 512 + hf * 256 + l32 * 8) = pack8(f);
    }
  }
}

// ---------------------------------------------------------------------------
// proj R11: LDS-free MFMA GEMM, one O0/O1 pixel-group pair per block (ILP 2),
// direct stores. Grid 1024: [0,256) q, [256,512) k, [512,1024) v.
// 3 blocks/CU (was 2), half the serial chain per block.
// ---------------------------------------------------------------------------
__global__ __launch_bounds__(256, 3) void proj_mfma(
    const __hip_bfloat16* __restrict__ xf, const __hip_bfloat16* __restrict__ zf,
    const __hip_bfloat16* __restrict__ wfr,
    const float* __restrict__ bq, const float* __restrict__ bk,
    const float* __restrict__ bv,
    __hip_bfloat16* __restrict__ qp, __hip_bfloat16* __restrict__ kp,
    __hip_bfloat16* __restrict__ vp)
{
  const int bi = blockIdx.x;
  int mode, b, pg0, h = 0;
  if (bi < 512) { mode = bi >> 8; b = (bi >> 6) & 3; pg0 = (bi & 63) * 2; }
  else { int j = bi - 512; mode = 2; b = j >> 7; pg0 = ((j >> 1) & 63) * 2; h = j & 1; }
  const int tid = threadIdx.x, w = tid >> 6, lane = tid & 63,
            l32 = lane & 31, half = lane >> 5;

  const __hip_bfloat16* X = (mode == 0) ? xf : zf;
  const int wtile = (mode == 2 ? h * 4 : 0) + w;
  const int wbase = (mode == 0) ? 0 : (mode == 1) ? 32768 : 65536;
  const __hip_bfloat16* wp = wfr + wbase + wtile * 8192 + lane * 8;
  bf16x8 wfg[16];
#pragma unroll
  for (int cs = 0; cs < 16; cs++) wfg[cs] = *(const bf16x8*)(wp + cs * 512);

  const float* bias = (mode == 0) ? bq : (mode == 1) ? bk : bv;
  const int ochb = (mode == 2 ? h * 128 : 0) + w * 32;
  float bb[16];
#pragma unroll
  for (int r = 0; r < 16; r++)
    bb[r] = bias[ochb + (r & 3) + 8 * (r >> 2) + 4 * half];

  const int t4 = (l32 >> 2) & 3;
  const int kperm = (t4 == 1 || t4 == 2) ? (l32 ^ 12) : l32;

  const __hip_bfloat16* xb0 = X + ((size_t)(b * 128 + pg0)) * 8192 + lane * 8;
  const __hip_bfloat16* xb1 = xb0 + 8192;
  f32x16 O0 = {}, O1 = {};
#pragma unroll
  for (int cs = 0; cs < 16; cs++) {
    bf16x8 xr0 = *(const bf16x8*)(xb0 + cs * 512);
    bf16x8 xr1 = *(const bf16x8*)(xb1 + cs * 512);
    O0 = __builtin_amdgcn_mfma_f32_32x32x16_bf16(wfg[cs], xr0, O0, 0, 0, 0);
    O1 = __builtin_amdgcn_mfma_f32_32x32x16_bf16(wfg[cs], xr1, O1, 0, 0, 0);
  }
#pragma unroll
  for (int p = 0; p < 2; p++) {
    const f32x16& O = p ? O1 : O0;
    const int pg = pg0 + p;
    if (mode == 0) {
      __hip_bfloat16* qb = qp + ((size_t)(b * 128 + pg)) * 4096;
#pragma unroll
      for (int r = 0; r < 16; r++) {
        int oc = ochb + (r & 3) + 8 * (r >> 2) + 4 * half;
        qb[(oc >> 4) * 512 + ((oc >> 3) & 1) * 256 + l32 * 8 + (oc & 7)] =
            __float2bfloat16((O[r] + bb[r]) * LOG2E);
      }
    } else if (mode == 1) {
      __hip_bfloat16* kb = kp + ((size_t)(b * 128 + pg)) * 4096;
#pragma unroll
      for (int r = 0; r < 16; r++) {
        int oc = ochb + (r & 3) + 8 * (r >> 2) + 4 * half;
        kb[(oc >> 4) * 512 + ((oc >> 3) & 1) * 256 + kperm * 8 + (oc & 7)] =
            __float2bfloat16(O[r] + bb[r]);
      }
    } else {
      __hip_bfloat16* vb = vp + ((size_t)(b * 128 + pg)) * 8192
          + (h * 4 + w) * 1024 + (l32 >> 4) * 512 + ((l32 >> 3) & 1) * 256
          + (l32 & 7);
#pragma unroll
      for (int r = 0; r < 16; r++) {
        int rr = (r & 3) + 8 * (r >> 2) + 4 * half;
        vb[rr * 8] = __float2bfloat16(O[r] + bb[r]);
      }
    }
  }
}

// ---------------------------------------------------------------------------
// attn R11: R8 body verbatim, templated on SPLIT.
// SPLIT=0: grid 512, 64 tiles, writes out directly (exact R8 fallback).
// SPLIT=1: grid 1024, kt2 = key half, 32 tiles, writes unnormalized
//          O-partials (f32) + l-partials to workspace.
// ---------------------------------------------------------------------------
struct AttnSmem {
  union {
    __hip_bfloat16 kbuf[2][8192];   // 2 x 16 KiB
    float ostage[256][33];          // epilogue [ch][q], pad 33
  } u;
  float redu[4][32];
  float rinv[32];
};

template <int SPLIT>
__global__ __launch_bounds__(256, 3) void attn_kernel(
    const __hip_bfloat16* __restrict__ qv, const __hip_bfloat16* __restrict__ kv,
    const __hip_bfloat16* __restrict__ vv,
    const float* __restrict__ x_main, const float* __restrict__ gammap,
    float* __restrict__ out,
    float* __restrict__ part, float* __restrict__ lpart)
{
  __shared__ AttnSmem sm;
  const int i  = blockIdx.x;           // 512 (SPLIT=0) or 1024 (SPLIT=1)
  const int b  = (i & 7) >> 1;         // XCD-pair -> batch (K+V L2-resident)
  int qt, kt2;
  if (SPLIT) { int j = i >> 3; kt2 = j >> 6; qt = ((j & 63) << 1) | (i & 1); }
  else       { kt2 = 0;        qt = ((i >> 3) << 1) | (i & 1); }
  const int NT = SPLIT ? 32 : 64;      // tiles of 64 keys each
  const int sbase = kt2 * 32;
  const int n0 = qt * 32;
  const int tid  = threadIdx.x;
  const int w    = tid >> 6, lane = tid & 63, l32 = lane & 31;
  const int kh   = w >> 1, chh = w & 1;
  const int t0   = qt & (NT - 1);      // stagger: de-correlate block streams

  // Q B-fragments (coalesced frag-order)
  bf16x8 qf[8];
  {
    const __hip_bfloat16* qb = qv + ((size_t)(b * 128 + qt)) * 4096 + lane * 8;
#pragma unroll
    for (int cs = 0; cs < 8; cs++) qf[cs] = *(const bf16x8*)(qb + cs * 512);
  }

  const __hip_bfloat16* kg = kv + (size_t)(b * 128) * 4096;
  const __hip_bfloat16* vg = vv + (size_t)(b * 128) * 8192;

  auto stage = [&](int ta, int par) {
    __hip_bfloat16* kd = sm.u.kbuf[par];
    const __hip_bfloat16* ksrc = kg + (size_t)(sbase + ta) * 8192 + lane * 8;
#pragma unroll
    for (int c = 0; c < 4; c++) {
      int ck = w * 4 + c;
      dma16(ksrc + ck * 512, kd + ck * 512 + lane * 8);
    }
  };

  f32x16 Oacc[4];   // O^T: 128 ch (chh half) x 32 q, partial over kh keys
#pragma unroll
  for (int c = 0; c < 4; c++)
#pragma unroll
    for (int r = 0; r < 16; r++) Oacc[c][r] = 0.f;

  float l_lane = 0.f;

  // one tile: V loads first (latency hides behind QK LDS chain), then
  // S^T = K Q, P = exp2(S-64) (shuffle-free via K perm), PV.
  auto body = [&](int par, int ta) {
    const __hip_bfloat16* vb = vg + (size_t)((sbase + ta) * 2 + kh) * 8192
                             + chh * 4096 + lane * 8;
    bf16x8 Vc[8];
#pragma unroll
    for (int c = 0; c < 4; c++) {
      Vc[2 * c]     = *(const bf16x8*)(vb + c * 1024);
      Vc[2 * c + 1] = *(const bf16x8*)(vb + c * 1024 + 512);
    }
    const __hip_bfloat16* kbase = sm.u.kbuf[par] + kh * 4096 + lane * 8;
    f32x16 S = {};
#pragma unroll
    for (int cs = 0; cs < 8; cs++) {
      bf16x8 kf = *(const bf16x8*)(kbase + cs * 512);
      S = __builtin_amdgcn_mfma_f32_32x32x16_bf16(kf, qf[cs], S, 0, 0, 0);
    }
    unsigned p2[8];
    float lsub = 0.f;
#pragma unroll
    for (int i2 = 0; i2 < 8; i2++) {
      float a = exp2f(S[2 * i2]     - 64.0f);
      float c = exp2f(S[2 * i2 + 1] - 64.0f);
      lsub += a + c;
      union { __hip_bfloat162 h; unsigned u; } cv;
      cv.h = __float22bfloat162_rn(float2{a, c});
      p2[i2] = cv.u;
    }
    l_lane += lsub;
    U4 f0, f1;
    f0.u[0] = p2[0]; f0.u[1] = p2[1]; f0.u[2] = p2[2]; f0.u[3] = p2[3];
    f1.u[0] = p2[4]; f1.u[1] = p2[5]; f1.u[2] = p2[6]; f1.u[3] = p2[7];
    const bf16x8 pf0 = f0.v, pf1 = f1.v;
#pragma unroll
    for (int c = 0; c < 4; c++) {
      Oacc[c] = __builtin_amdgcn_mfma_f32_32x32x16_bf16(Vc[2 * c],     pf0, Oacc[c], 0, 0, 0);
      Oacc[c] = __builtin_amdgcn_mfma_f32_32x32x16_bf16(Vc[2 * c + 1], pf1, Oacc[c], 0, 0, 0);
    }
  };

  // ---- pipelined main loop, 1 barrier/tile, staggered tile order ----
  stage(t0, 0);
  __syncthreads();                 // tile t0 landed
  stage((t0 + 1) & (NT - 1), 1);
  body(0, t0);
#pragma unroll 1
  for (int lt = 1; lt < NT; ++lt) {
    __syncthreads();               // drains stage issued one body ago
    if (lt < NT - 1) stage((lt + 1 + t0) & (NT - 1), (lt + 1) & 1);
    body(lt & 1, (lt + t0) & (NT - 1));
  }

  // ---- epilogue: publish l, kh-merge via ostage (ch rows), writeout ----
  float lfull = l_lane + __shfl_xor(l_lane, 32);
  if (lane < 32) sm.redu[w][l32] = lfull;
  __syncthreads();                 // kbuf reads done; redu published
  const int hb = lane >> 5;
  const int pblk = SPLIT ? ((b * 128 + qt) * 2 + kt2) : 0;
  if (kh == 0) {
#pragma unroll
    for (int c = 0; c < 4; c++) {
#pragma unroll
      for (int r = 0; r < 16; r++) {
        int ch = (chh * 4 + c) * 32 + (r & 3) + 8 * (r >> 2) + 4 * hb;
        sm.u.ostage[ch][l32] = Oacc[c][r];
      }
    }
  }
  if (SPLIT) {
    if (tid < 32)
      lpart[(size_t)pblk * 32 + tid] = sm.redu[0][tid] + sm.redu[2][tid];
  } else {
    if (tid < 32) sm.rinv[tid] = 1.0f / (sm.redu[0][tid] + sm.redu[2][tid]);
  }
  __syncthreads();
  if (kh == 1) {
#pragma unroll
    for (int c = 0; c < 4; c++) {
#pragma unroll
      for (int r = 0; r < 16; r++) {
        int ch = (chh * 4 + c) * 32 + (r & 3) + 8 * (r >> 2) + 4 * hb;
        sm.u.ostage[ch][l32] += Oacc[c][r];
      }
    }
  }
  __syncthreads();

  const int pix = tid & 31;
  if (SPLIT) {
    float* pb = part + (size_t)pblk * 8192;
#pragma unroll
    for (int j = 0; j < 32; ++j) {
      int ch = (tid >> 5) * 32 + j;
      pb[ch * 32 + pix] = sm.u.ostage[ch][pix];
    }
  } else {
    const float gmm = gammap[0];
    const float ri = sm.rinv[pix];
#pragma unroll
    for (int j = 0; j < 32; ++j) {
      int ch = (tid >> 5) * 32 + j;
      size_t g = ((size_t)(b * 256 + ch)) * 4096 + n0 + pix;
      out[g] = gmm * sm.u.ostage[ch][pix] * ri + x_main[g];
    }
  }
}

// ---------------------------------------------------------------------------
// merge: (O0 + O1) / (l0 + l1) * gamma + x_main. Grid 512 = (b, qt).
// BW-bound: 32MB partials + 16.7MB x + 16.7MB out ≈ 65MB ≈ 11 µs floor.
// ---------------------------------------------------------------------------
__global__ __launch_bounds__(256) void merge_kernel(
    const float* __restrict__ part, const float* __restrict__ lpart,
    const float* __restrict__ x_main, const float* __restrict__ gammap,
    float* __restrict__ out)
{
  const int i = blockIdx.x;            // 512
  const int b = i >> 7, qt = i & 127, n0 = qt * 32;
  const int tid = threadIdx.x, pix = tid & 31;
  const size_t pb = (size_t)((b * 128 + qt) * 2) * 8192;
  const float* lp = lpart + (size_t)((b * 128 + qt) * 2) * 32;
  const float rv = gammap[0] / (lp[pix] + lp[32 + pix]);
#pragma unroll
  for (int j = 0; j < 32; ++j) {
    int ch = (tid >> 5) * 32 + j;
    size_t g = ((size_t)(b * 256 + ch)) * 4096 + n0 + pix;
    float o = (part[pb + ch * 32 + pix] + part[pb + 8192 + ch * 32 + pix]) * rv;
    out[g] = o + x_main[g];
  }
}

// ---------------------------------------------------------------------------
extern "C" void kernel_launch(void* const* d_in, const int* in_sizes, int n_in,
                              void* d_out, int out_size, void* d_ws, size_t ws_size,
                              hipStream_t stream) {
  (void)in_sizes; (void)n_in; (void)out_size;
  const float* x  = (const float*)d_in[0];
  const float* z  = (const float*)d_in[1];
  const float* Wq = (const float*)d_in[2];
  const float* bq = (const float*)d_in[3];
  const float* Wk = (const float*)d_in[4];
  const float* bk = (const float*)d_in[5];
  const float* Wv = (const float*)d_in[6];
  const float* bv = (const float*)d_in[7];
  const float* gm = (const float*)d_in[8];
  float* out = (float*)d_out;

  char* ws = (char*)d_ws;
  const size_t MB = 1024 * 1024;
  __hip_bfloat16* qp  = (__hip_bfloat16*)(ws);             // 4 MiB
  __hip_bfloat16* kp  = (__hip_bfloat16*)(ws + 4 * MB);    // 4 MiB
  __hip_bfloat16* vp  = (__hip_bfloat16*)(ws + 8 * MB);    // 8 MiB
  __hip_bfloat16* xfp = (__hip_bfloat16*)(ws + 16 * MB);   // 8 MiB
  __hip_bfloat16* zfp = (__hip_bfloat16*)(ws + 24 * MB);   // 8 MiB
  __hip_bfloat16* wfp = (__hip_bfloat16*)(ws + 32 * MB);   // 256 KiB
  float* part  = (float*)(ws + 33 * MB);                   // 32 MiB (split)
  float* lpart = (float*)(ws + 65 * MB);                   // 128 KiB (split)

  const bool split = ws_size >= 66 * MB;

  prep_kernel<<<516, 256, 0, stream>>>(x, z, Wq, Wk, Wv, xfp, zfp, wfp);
  proj_mfma  <<<1024, 256, 0, stream>>>(xfp, zfp, wfp, bq, bk, bv, qp, kp, vp);
  if (split) {
    attn_kernel<1><<<1024, 256, 0, stream>>>(qp, kp, vp, x, gm, out, part, lpart);
    merge_kernel<<<512, 256, 0, stream>>>(part, lpart, x, gm, out);
  } else {
    attn_kernel<0><<<512, 256, 0, stream>>>(qp, kp, vp, x, gm, out, part, lpart);
  }
}

// Round 6
// 212.637 us; speedup vs baseline: 1.5138x; 1.0331x over previous
//
#include <hip/hip_runtime.h>
#include <hip/hip_bf16.h>

// CrossAttentionFusion: B=4, C=Cs=256, CI=128, H=W=64 -> N=M=4096
// R12 = R8 math, cross-tile software-pipelined attn body:
//  - R9: +waves starves regs (2x worse). R10: dedup adds sync+conflicts
//    (+30us). R11: split-K 3 blocks/CU moved attn only 113->106.5 and merge
//    ate it => per-tile serial chain (QK -> exp -> PV -> barrier) is the wall,
//    ~85% exposed latency per tile.
//  - R12 body: per iter compute QK(t) -> PV(t-1) -> softmax(t). PV issue
//    covers S's MFMA latency; pf/Oacc deps span iterations; V(t) loaded one
//    iteration before its PV (full-iter latency cover). V double-buffered in
//    regs with STATIC names (VcA/VcB, 2x hand-unrolled loop). Single-pass
//    output (no split/merge). launch_bounds(256,2): ~180 regs, no spills;
//    2 blocks/CU — latency hidden by ILP now, not TLP.
//  - proj: R11 1024-grid (one O0/O1 pair per block, 3 blocks/CU). prep same.
//
// qk-frag (Q B-op / K A-op), per 32-row group g:
//   addr = g*4096 + (ch>>4)*512 + ((ch>>3)&1)*256 + row*8 + (ch&7)
//   (K rows permuted: row = l32^12 if (l32>>2)&3 in {1,2} -> shuffle-free PV)
// V-frag (PV A-op), per 32-key group g: addr = g*8192 + (ch>>5)*1024
//   + ((key>>4)&1)*512 + ((key>>3)&1)*256 + (ch&31)*8 + (key&7)

typedef __bf16  bf16x8  __attribute__((ext_vector_type(8)));
typedef float   f32x16  __attribute__((ext_vector_type(16)));

#define LOG2E 1.4426950408889634f

union BF8 { __hip_bfloat162 h[4]; bf16x8 v; };
union U4  { unsigned u[4]; bf16x8 v; };

__device__ inline bf16x8 pack8(const float f[8]) {
  BF8 u;
#pragma unroll
  for (int i = 0; i < 4; i++)
    u.h[i] = __float22bfloat162_rn(float2{f[2 * i], f[2 * i + 1]});
  return u.v;
}

__device__ inline void dma16(const void* g, void* l) {
  __builtin_amdgcn_global_load_lds(
      (const __attribute__((address_space(1))) unsigned int*)g,
      (__attribute__((address_space(3))) unsigned int*)l, 16, 0, 0);
}

// ---------------------------------------------------------------------------
// prep: blocks [0,512): x/z -> X-frag bf16 (LDS transpose, float4 loads);
//       blocks [512,516): W -> W-frag bf16.  (unchanged from R8)
// ---------------------------------------------------------------------------
__global__ __launch_bounds__(256) void prep_kernel(
    const float* __restrict__ x, const float* __restrict__ z,
    const float* __restrict__ Wq, const float* __restrict__ Wk,
    const float* __restrict__ Wv,
    __hip_bfloat16* __restrict__ xf, __hip_bfloat16* __restrict__ zf,
    __hip_bfloat16* __restrict__ wfr)
{
  __shared__ float lds[256 * 68];   // pitch 68: 16B-aligned rows, conflict-free
  const int bi = blockIdx.x;
  const int tid = threadIdx.x;
  if (bi < 512) {
    const int sel = bi >> 8;
    const int b   = (bi >> 6) & 3;
    const int pc  = bi & 63;
    const float* in = sel ? z : x;
    __hip_bfloat16* outp = sel ? zf : xf;
    const size_t ib = (size_t)b * 256 * 4096 + pc * 64;
    const int pix4 = (tid & 15) * 4;
#pragma unroll
    for (int it = 0; it < 16; it++) {
      int ch = it * 16 + (tid >> 4);
      float4 v4 = *(const float4*)&in[ib + (size_t)ch * 4096 + pix4];
      *(float4*)&lds[ch * 68 + pix4] = v4;
    }
    __syncthreads();
    const size_t ob = ((size_t)(b * 128 + pc * 2)) * 8192;
#pragma unroll
    for (int i = 0; i < 8; i++) {
      int c = i * 256 + tid;
      int grp = c >> 10, cs = (c >> 6) & 15, rem = c & 63;
      int hf = rem >> 5, l32 = rem & 31;
      float f[8];
      int chb = cs * 16 + hf * 8;
#pragma unroll
      for (int j = 0; j < 8; j++)
        f[j] = lds[(chb + j) * 68 + grp * 32 + l32];
      *(bf16x8*)(outp + ob + grp * 8192 + cs * 512 + hf * 256 + l32 * 8) =
          pack8(f);
    }
  } else {
    const int base = (bi - 512) * 4096;
#pragma unroll
    for (int i = 0; i < 16; i++) {
      int c = base + i * 256 + tid;
      const float* Ws; __hip_bfloat16* dst; int rc;
      if (c < 4096)      { Ws = Wq; dst = wfr;          rc = c; }
      else if (c < 8192) { Ws = Wk; dst = wfr + 32768;  rc = c - 4096; }
      else               { Ws = Wv; dst = wfr + 65536;  rc = c - 8192; }
      int ot = rc >> 10, cs = (rc >> 6) & 15, rem = rc & 63;
      int hf = rem >> 5, l32 = rem & 31;
      const float* src = Ws + (ot * 32 + l32) * 256 + cs * 16 + hf * 8;
      float f[8];
#pragma unroll
      for (int j = 0; j < 8; j++) f[j] = src[j];
      *(bf16x8*)(dst + ot * 8192 + cs * 512 + hf * 256 + l32 * 8) = pack8(f);
    }
  }
}

// ---------------------------------------------------------------------------
// proj: LDS-free MFMA GEMM, one O0/O1 pixel-group pair per block (ILP 2),
// direct stores. Grid 1024: [0,256) q, [256,512) k, [512,1024) v.  (R11)
// ---------------------------------------------------------------------------
__global__ __launch_bounds__(256, 3) void proj_mfma(
    const __hip_bfloat16* __restrict__ xf, const __hip_bfloat16* __restrict__ zf,
    const __hip_bfloat16* __restrict__ wfr,
    const float* __restrict__ bq, const float* __restrict__ bk,
    const float* __restrict__ bv,
    __hip_bfloat16* __restrict__ qp, __hip_bfloat16* __restrict__ kp,
    __hip_bfloat16* __restrict__ vp)
{
  const int bi = blockIdx.x;
  int mode, b, pg0, h = 0;
  if (bi < 512) { mode = bi >> 8; b = (bi >> 6) & 3; pg0 = (bi & 63) * 2; }
  else { int j = bi - 512; mode = 2; b = j >> 7; pg0 = ((j >> 1) & 63) * 2; h = j & 1; }
  const int tid = threadIdx.x, w = tid >> 6, lane = tid & 63,
            l32 = lane & 31, half = lane >> 5;

  const __hip_bfloat16* X = (mode == 0) ? xf : zf;
  const int wtile = (mode == 2 ? h * 4 : 0) + w;
  const int wbase = (mode == 0) ? 0 : (mode == 1) ? 32768 : 65536;
  const __hip_bfloat16* wp = wfr + wbase + wtile * 8192 + lane * 8;
  bf16x8 wfg[16];
#pragma unroll
  for (int cs = 0; cs < 16; cs++) wfg[cs] = *(const bf16x8*)(wp + cs * 512);

  const float* bias = (mode == 0) ? bq : (mode == 1) ? bk : bv;
  const int ochb = (mode == 2 ? h * 128 : 0) + w * 32;
  float bb[16];
#pragma unroll
  for (int r = 0; r < 16; r++)
    bb[r] = bias[ochb + (r & 3) + 8 * (r >> 2) + 4 * half];

  const int t4 = (l32 >> 2) & 3;
  const int kperm = (t4 == 1 || t4 == 2) ? (l32 ^ 12) : l32;

  const __hip_bfloat16* xb0 = X + ((size_t)(b * 128 + pg0)) * 8192 + lane * 8;
  const __hip_bfloat16* xb1 = xb0 + 8192;
  f32x16 O0 = {}, O1 = {};
#pragma unroll
  for (int cs = 0; cs < 16; cs++) {
    bf16x8 xr0 = *(const bf16x8*)(xb0 + cs * 512);
    bf16x8 xr1 = *(const bf16x8*)(xb1 + cs * 512);
    O0 = __builtin_amdgcn_mfma_f32_32x32x16_bf16(wfg[cs], xr0, O0, 0, 0, 0);
    O1 = __builtin_amdgcn_mfma_f32_32x32x16_bf16(wfg[cs], xr1, O1, 0, 0, 0);
  }
#pragma unroll
  for (int p = 0; p < 2; p++) {
    const f32x16& O = p ? O1 : O0;
    const int pg = pg0 + p;
    if (mode == 0) {
      __hip_bfloat16* qb = qp + ((size_t)(b * 128 + pg)) * 4096;
#pragma unroll
      for (int r = 0; r < 16; r++) {
        int oc = ochb + (r & 3) + 8 * (r >> 2) + 4 * half;
        qb[(oc >> 4) * 512 + ((oc >> 3) & 1) * 256 + l32 * 8 + (oc & 7)] =
            __float2bfloat16((O[r] + bb[r]) * LOG2E);
      }
    } else if (mode == 1) {
      __hip_bfloat16* kb = kp + ((size_t)(b * 128 + pg)) * 4096;
#pragma unroll
      for (int r = 0; r < 16; r++) {
        int oc = ochb + (r & 3) + 8 * (r >> 2) + 4 * half;
        kb[(oc >> 4) * 512 + ((oc >> 3) & 1) * 256 + kperm * 8 + (oc & 7)] =
            __float2bfloat16(O[r] + bb[r]);
      }
    } else {
      __hip_bfloat16* vb = vp + ((size_t)(b * 128 + pg)) * 8192
          + (h * 4 + w) * 1024 + (l32 >> 4) * 512 + ((l32 >> 3) & 1) * 256
          + (l32 & 7);
#pragma unroll
      for (int r = 0; r < 16; r++) {
        int rr = (r & 3) + 8 * (r >> 2) + 4 * half;
        vb[rr * 8] = __float2bfloat16(O[r] + bb[r]);
      }
    }
  }
}

// ---------------------------------------------------------------------------
// attn R12: R8 mapping (grid 512, 4 waves = (kh, chh)), software-pipelined
// body: per iter QK(t) -> PV(t-1) -> softmax(t); V double-buffered in regs
// (VcA/VcB static, 2x unrolled loop); K DMA+LDS dbuf, 1 barrier/tile;
// tile-order stagger t0 = qt & 63 kept. Single-pass output.
// ---------------------------------------------------------------------------
struct AttnSmem {
  union {
    __hip_bfloat16 kbuf[2][8192];   // 2 x 16 KiB
    float ostage[256][33];          // epilogue [ch][q], pad 33
  } u;
  float redu[4][32];
  float rinv[32];
};

__global__ __launch_bounds__(256, 2) void attn_kernel(
    const __hip_bfloat16* __restrict__ qv, const __hip_bfloat16* __restrict__ kv,
    const __hip_bfloat16* __restrict__ vv,
    const float* __restrict__ x_main, const float* __restrict__ gammap,
    float* __restrict__ out)
{
  __shared__ AttnSmem sm;
  const int i  = blockIdx.x;           // 512 blocks
  const int b  = (i & 7) >> 1;         // XCD-pair -> batch (K+V L2-resident)
  const int qt = ((i >> 3) << 1) | (i & 1);
  const int n0 = qt * 32;
  const int tid  = threadIdx.x;
  const int w    = tid >> 6, lane = tid & 63, l32 = lane & 31;
  const int kh   = w >> 1, chh = w & 1;
  const int t0   = qt & 63;            // stagger: de-correlate block streams

  // Q B-fragments (coalesced frag-order)
  bf16x8 qf[8];
  {
    const __hip_bfloat16* qb = qv + ((size_t)(b * 128 + qt)) * 4096 + lane * 8;
#pragma unroll
    for (int cs = 0; cs < 8; cs++) qf[cs] = *(const bf16x8*)(qb + cs * 512);
  }

  const __hip_bfloat16* kg = kv + (size_t)(b * 128) * 4096;
  const __hip_bfloat16* vg = vv + (size_t)(b * 128) * 8192;

  auto stage = [&](int ta, int par) {
    __hip_bfloat16* kd = sm.u.kbuf[par];
    const __hip_bfloat16* ksrc = kg + (size_t)ta * 8192 + lane * 8;
#pragma unroll
    for (int c = 0; c < 4; c++) {
      int ck = w * 4 + c;
      dma16(ksrc + ck * 512, kd + ck * 512 + lane * 8);
    }
  };

  f32x16 Oacc[4];   // O^T: 128 ch (chh half) x 32 q, partial over kh keys
#pragma unroll
  for (int c = 0; c < 4; c++)
#pragma unroll
    for (int r = 0; r < 16; r++) Oacc[c][r] = 0.f;

  float l_lane = 0.f;

  auto loadV = [&](int ta, bf16x8* Vc) {
    const __hip_bfloat16* vb = vg + (size_t)(ta * 2 + kh) * 8192
                             + chh * 4096 + lane * 8;
#pragma unroll
    for (int c = 0; c < 4; c++) {
      Vc[2 * c]     = *(const bf16x8*)(vb + c * 1024);
      Vc[2 * c + 1] = *(const bf16x8*)(vb + c * 1024 + 512);
    }
  };

  auto qk = [&](int par) -> f32x16 {
    const __hip_bfloat16* kbase = sm.u.kbuf[par] + kh * 4096 + lane * 8;
    f32x16 S = {};
#pragma unroll
    for (int cs = 0; cs < 8; cs++) {
      bf16x8 kf = *(const bf16x8*)(kbase + cs * 512);
      S = __builtin_amdgcn_mfma_f32_32x32x16_bf16(kf, qf[cs], S, 0, 0, 0);
    }
    return S;
  };

  auto softmax = [&](const f32x16& S, bf16x8& pf0, bf16x8& pf1) {
    unsigned p2[8];
    float lsub = 0.f;
#pragma unroll
    for (int i2 = 0; i2 < 8; i2++) {
      float a = exp2f(S[2 * i2]     - 64.0f);
      float c = exp2f(S[2 * i2 + 1] - 64.0f);
      lsub += a + c;
      union { __hip_bfloat162 h; unsigned u; } cv;
      cv.h = __float22bfloat162_rn(float2{a, c});
      p2[i2] = cv.u;
    }
    l_lane += lsub;
    U4 f0, f1;
    f0.u[0] = p2[0]; f0.u[1] = p2[1]; f0.u[2] = p2[2]; f0.u[3] = p2[3];
    f1.u[0] = p2[4]; f1.u[1] = p2[5]; f1.u[2] = p2[6]; f1.u[3] = p2[7];
    pf0 = f0.v; pf1 = f1.v;
  };

  auto pv = [&](const bf16x8* Vc, bf16x8 pf0, bf16x8 pf1) {
#pragma unroll
    for (int c = 0; c < 4; c++) {
      Oacc[c] = __builtin_amdgcn_mfma_f32_32x32x16_bf16(Vc[2 * c],     pf0, Oacc[c], 0, 0, 0);
      Oacc[c] = __builtin_amdgcn_mfma_f32_32x32x16_bf16(Vc[2 * c + 1], pf1, Oacc[c], 0, 0, 0);
    }
  };

  bf16x8 VcA[8], VcB[8];
  bf16x8 pf0, pf1;

  // ---- prologue: tile t0 (QK + softmax only; its PV runs next iter) ----
  stage(t0, 0);
  __syncthreads();                 // K(t0) landed
  stage((t0 + 1) & 63, 1);
  loadV(t0, VcA);
  {
    f32x16 S = qk(0);
    softmax(S, pf0, pf1);
  }

  // ---- main loop: 31 unrolled pairs (lt = 1..62), static Vc swap ----
#pragma unroll 1
  for (int lt = 1; lt < 63; lt += 2) {
    // iter lt: par 1, prev V in VcA
    __syncthreads();               // K(t0+lt) landed; drains prior stage
    stage((lt + 1 + t0) & 63, 0);
    loadV((lt + t0) & 63, VcB);
    {
      f32x16 S = qk(1);
      pv(VcA, pf0, pf1);           // PV(t-1) covers S's MFMA latency
      softmax(S, pf0, pf1);
    }
    // iter lt+1: par 0, prev V in VcB
    __syncthreads();
    stage((lt + 2 + t0) & 63, 1);
    loadV((lt + 1 + t0) & 63, VcA);
    {
      f32x16 S = qk(0);
      pv(VcB, pf0, pf1);
      softmax(S, pf0, pf1);
    }
  }
  // ---- final tile lt = 63: par 1, prev V in VcA; no further stage ----
  __syncthreads();
  loadV((63 + t0) & 63, VcB);
  {
    f32x16 S = qk(1);
    pv(VcA, pf0, pf1);
    softmax(S, pf0, pf1);
  }
  pv(VcB, pf0, pf1);               // drain: PV of last tile

  // ---- epilogue: publish l, kh-merge via ostage (ch rows), writeout ----
  float lfull = l_lane + __shfl_xor(l_lane, 32);
  if (lane < 32) sm.redu[w][l32] = lfull;
  __syncthreads();                 // kbuf reads done; redu published
  const int hb = lane >> 5;
  if (kh == 0) {
#pragma unroll
    for (int c = 0; c < 4; c++) {
#pragma unroll
      for (int r = 0; r < 16; r++) {
        int ch = (chh * 4 + c) * 32 + (r & 3) + 8 * (r >> 2) + 4 * hb;
        sm.u.ostage[ch][l32] = Oacc[c][r];
      }
    }
  }
  if (tid < 32) sm.rinv[tid] = 1.0f / (sm.redu[0][tid] + sm.redu[2][tid]);
  __syncthreads();
  if (kh == 1) {
#pragma unroll
    for (int c = 0; c < 4; c++) {
#pragma unroll
      for (int r = 0; r < 16; r++) {
        int ch = (chh * 4 + c) * 32 + (r & 3) + 8 * (r >> 2) + 4 * hb;
        sm.u.ostage[ch][l32] += Oacc[c][r];
      }
    }
  }
  __syncthreads();

  const float gmm = gammap[0];
  const int pix = tid & 31;
  const float ri = sm.rinv[pix];
#pragma unroll
  for (int j = 0; j < 32; ++j) {
    int ch = (tid >> 5) * 32 + j;
    size_t g = ((size_t)(b * 256 + ch)) * 4096 + n0 + pix;
    out[g] = gmm * sm.u.ostage[ch][pix] * ri + x_main[g];
  }
}

// ---------------------------------------------------------------------------
extern "C" void kernel_launch(void* const* d_in, const int* in_sizes, int n_in,
                              void* d_out, int out_size, void* d_ws, size_t ws_size,
                              hipStream_t stream) {
  (void)in_sizes; (void)n_in; (void)out_size; (void)ws_size;
  const float* x  = (const float*)d_in[0];
  const float* z  = (const float*)d_in[1];
  const float* Wq = (const float*)d_in[2];
  const float* bq = (const float*)d_in[3];
  const float* Wk = (const float*)d_in[4];
  const float* bk = (const float*)d_in[5];
  const float* Wv = (const float*)d_in[6];
  const float* bv = (const float*)d_in[7];
  const float* gm = (const float*)d_in[8];
  float* out = (float*)d_out;

  char* ws = (char*)d_ws;
  const size_t MB = 1024 * 1024;
  __hip_bfloat16* qp  = (__hip_bfloat16*)(ws);             // 4 MiB
  __hip_bfloat16* kp  = (__hip_bfloat16*)(ws + 4 * MB);    // 4 MiB
  __hip_bfloat16* vp  = (__hip_bfloat16*)(ws + 8 * MB);    // 8 MiB
  __hip_bfloat16* xfp = (__hip_bfloat16*)(ws + 16 * MB);   // 8 MiB
  __hip_bfloat16* zfp = (__hip_bfloat16*)(ws + 24 * MB);   // 8 MiB
  __hip_bfloat16* wfp = (__hip_bfloat16*)(ws + 32 * MB);   // 256 KiB

  prep_kernel<<<516, 256, 0, stream>>>(x, z, Wq, Wk, Wv, xfp, zfp, wfp);
  proj_mfma  <<<1024, 256, 0, stream>>>(xfp, zfp, wfp, bq, bk, bv, qp, kp, vp);
  attn_kernel<<<512, 256, 0, stream>>>(qp, kp, vp, x, gm, out);
}

// Round 7
// 212.224 us; speedup vs baseline: 1.5168x; 1.0019x over previous
//
#include <hip/hip_runtime.h>
#include <hip/hip_bf16.h>

// CrossAttentionFusion: B=4, C=Cs=256, CI=128, H=W=64 -> N=M=4096
// R13 = R8 math + counted-vmcnt pipeline (T3/T4):
//  - Diagnosis closing R8..R12: __syncthreads() = s_waitcnt vmcnt(0)+s_barrier
//    force-drains the just-issued next-tile K-DMA EVERY tile -> per-tile
//    period = DMA completion under L2 contention (~4274cyc), not issue (~800).
//    R11 (+TLP) -6%, R12 (reorder) 0%, R10 (+barrier) +27% all consistent.
//  - Fix: (1) kbuf[3], stage distance 2 (DMA has ~2 bodies to land);
//    (2) V loads issued BEFORE stage DMA + sched_barrier(0) pin -> FIFO makes
//    PV's compiler V-wait = vmcnt(4), proving dma(t+1) done pre-barrier;
//    (3) raw s_barrier (sched_barrier(0) fenced both sides) in main loop --
//    vmcnt never drains to 0 (T4). __syncthreads only prologue/epilogue.
//  - Body math/order identical to R8: V -> QK(LDS) -> softmax -> PV.
//  - proj: R11 1024-grid. prep unchanged.
//
// qk-frag (Q B-op / K A-op), per 32-row group g:
//   addr = g*4096 + (ch>>4)*512 + ((ch>>3)&1)*256 + row*8 + (ch&7)
//   (K rows permuted: row = l32^12 if (l32>>2)&3 in {1,2} -> shuffle-free PV)
// V-frag (PV A-op), per 32-key group g: addr = g*8192 + (ch>>5)*1024
//   + ((key>>4)&1)*512 + ((key>>3)&1)*256 + (ch&31)*8 + (key&7)

typedef __bf16  bf16x8  __attribute__((ext_vector_type(8)));
typedef float   f32x16  __attribute__((ext_vector_type(16)));

#define LOG2E 1.4426950408889634f

union BF8 { __hip_bfloat162 h[4]; bf16x8 v; };
union U4  { unsigned u[4]; bf16x8 v; };

__device__ inline bf16x8 pack8(const float f[8]) {
  BF8 u;
#pragma unroll
  for (int i = 0; i < 4; i++)
    u.h[i] = __float22bfloat162_rn(float2{f[2 * i], f[2 * i + 1]});
  return u.v;
}

__device__ inline void dma16(const void* g, void* l) {
  __builtin_amdgcn_global_load_lds(
      (const __attribute__((address_space(1))) unsigned int*)g,
      (__attribute__((address_space(3))) unsigned int*)l, 16, 0, 0);
}

// ---------------------------------------------------------------------------
// prep: blocks [0,512): x/z -> X-frag bf16 (LDS transpose, float4 loads);
//       blocks [512,516): W -> W-frag bf16.  (unchanged from R8)
// ---------------------------------------------------------------------------
__global__ __launch_bounds__(256) void prep_kernel(
    const float* __restrict__ x, const float* __restrict__ z,
    const float* __restrict__ Wq, const float* __restrict__ Wk,
    const float* __restrict__ Wv,
    __hip_bfloat16* __restrict__ xf, __hip_bfloat16* __restrict__ zf,
    __hip_bfloat16* __restrict__ wfr)
{
  __shared__ float lds[256 * 68];   // pitch 68: 16B-aligned rows, conflict-free
  const int bi = blockIdx.x;
  const int tid = threadIdx.x;
  if (bi < 512) {
    const int sel = bi >> 8;
    const int b   = (bi >> 6) & 3;
    const int pc  = bi & 63;
    const float* in = sel ? z : x;
    __hip_bfloat16* outp = sel ? zf : xf;
    const size_t ib = (size_t)b * 256 * 4096 + pc * 64;
    const int pix4 = (tid & 15) * 4;
#pragma unroll
    for (int it = 0; it < 16; it++) {
      int ch = it * 16 + (tid >> 4);
      float4 v4 = *(const float4*)&in[ib + (size_t)ch * 4096 + pix4];
      *(float4*)&lds[ch * 68 + pix4] = v4;
    }
    __syncthreads();
    const size_t ob = ((size_t)(b * 128 + pc * 2)) * 8192;
#pragma unroll
    for (int i = 0; i < 8; i++) {
      int c = i * 256 + tid;
      int grp = c >> 10, cs = (c >> 6) & 15, rem = c & 63;
      int hf = rem >> 5, l32 = rem & 31;
      float f[8];
      int chb = cs * 16 + hf * 8;
#pragma unroll
      for (int j = 0; j < 8; j++)
        f[j] = lds[(chb + j) * 68 + grp * 32 + l32];
      *(bf16x8*)(outp + ob + grp * 8192 + cs * 512 + hf * 256 + l32 * 8) =
          pack8(f);
    }
  } else {
    const int base = (bi - 512) * 4096;
#pragma unroll
    for (int i = 0; i < 16; i++) {
      int c = base + i * 256 + tid;
      const float* Ws; __hip_bfloat16* dst; int rc;
      if (c < 4096)      { Ws = Wq; dst = wfr;          rc = c; }
      else if (c < 8192) { Ws = Wk; dst = wfr + 32768;  rc = c - 4096; }
      else               { Ws = Wv; dst = wfr + 65536;  rc = c - 8192; }
      int ot = rc >> 10, cs = (rc >> 6) & 15, rem = rc & 63;
      int hf = rem >> 5, l32 = rem & 31;
      const float* src = Ws + (ot * 32 + l32) * 256 + cs * 16 + hf * 8;
      float f[8];
#pragma unroll
      for (int j = 0; j < 8; j++) f[j] = src[j];
      *(bf16x8*)(dst + ot * 8192 + cs * 512 + hf * 256 + l32 * 8) = pack8(f);
    }
  }
}

// ---------------------------------------------------------------------------
// proj: LDS-free MFMA GEMM, one O0/O1 pixel-group pair per block (ILP 2),
// direct stores. Grid 1024: [0,256) q, [256,512) k, [512,1024) v.  (R11)
// ---------------------------------------------------------------------------
__global__ __launch_bounds__(256, 3) void proj_mfma(
    const __hip_bfloat16* __restrict__ xf, const __hip_bfloat16* __restrict__ zf,
    const __hip_bfloat16* __restrict__ wfr,
    const float* __restrict__ bq, const float* __restrict__ bk,
    const float* __restrict__ bv,
    __hip_bfloat16* __restrict__ qp, __hip_bfloat16* __restrict__ kp,
    __hip_bfloat16* __restrict__ vp)
{
  const int bi = blockIdx.x;
  int mode, b, pg0, h = 0;
  if (bi < 512) { mode = bi >> 8; b = (bi >> 6) & 3; pg0 = (bi & 63) * 2; }
  else { int j = bi - 512; mode = 2; b = j >> 7; pg0 = ((j >> 1) & 63) * 2; h = j & 1; }
  const int tid = threadIdx.x, w = tid >> 6, lane = tid & 63,
            l32 = lane & 31, half = lane >> 5;

  const __hip_bfloat16* X = (mode == 0) ? xf : zf;
  const int wtile = (mode == 2 ? h * 4 : 0) + w;
  const int wbase = (mode == 0) ? 0 : (mode == 1) ? 32768 : 65536;
  const __hip_bfloat16* wp = wfr + wbase + wtile * 8192 + lane * 8;
  bf16x8 wfg[16];
#pragma unroll
  for (int cs = 0; cs < 16; cs++) wfg[cs] = *(const bf16x8*)(wp + cs * 512);

  const float* bias = (mode == 0) ? bq : (mode == 1) ? bk : bv;
  const int ochb = (mode == 2 ? h * 128 : 0) + w * 32;
  float bb[16];
#pragma unroll
  for (int r = 0; r < 16; r++)
    bb[r] = bias[ochb + (r & 3) + 8 * (r >> 2) + 4 * half];

  const int t4 = (l32 >> 2) & 3;
  const int kperm = (t4 == 1 || t4 == 2) ? (l32 ^ 12) : l32;

  const __hip_bfloat16* xb0 = X + ((size_t)(b * 128 + pg0)) * 8192 + lane * 8;
  const __hip_bfloat16* xb1 = xb0 + 8192;
  f32x16 O0 = {}, O1 = {};
#pragma unroll
  for (int cs = 0; cs < 16; cs++) {
    bf16x8 xr0 = *(const bf16x8*)(xb0 + cs * 512);
    bf16x8 xr1 = *(const bf16x8*)(xb1 + cs * 512);
    O0 = __builtin_amdgcn_mfma_f32_32x32x16_bf16(wfg[cs], xr0, O0, 0, 0, 0);
    O1 = __builtin_amdgcn_mfma_f32_32x32x16_bf16(wfg[cs], xr1, O1, 0, 0, 0);
  }
#pragma unroll
  for (int p = 0; p < 2; p++) {
    const f32x16& O = p ? O1 : O0;
    const int pg = pg0 + p;
    if (mode == 0) {
      __hip_bfloat16* qb = qp + ((size_t)(b * 128 + pg)) * 4096;
#pragma unroll
      for (int r = 0; r < 16; r++) {
        int oc = ochb + (r & 3) + 8 * (r >> 2) + 4 * half;
        qb[(oc >> 4) * 512 + ((oc >> 3) & 1) * 256 + l32 * 8 + (oc & 7)] =
            __float2bfloat16((O[r] + bb[r]) * LOG2E);
      }
    } else if (mode == 1) {
      __hip_bfloat16* kb = kp + ((size_t)(b * 128 + pg)) * 4096;
#pragma unroll
      for (int r = 0; r < 16; r++) {
        int oc = ochb + (r & 3) + 8 * (r >> 2) + 4 * half;
        kb[(oc >> 4) * 512 + ((oc >> 3) & 1) * 256 + kperm * 8 + (oc & 7)] =
            __float2bfloat16(O[r] + bb[r]);
      }
    } else {
      __hip_bfloat16* vb = vp + ((size_t)(b * 128 + pg)) * 8192
          + (h * 4 + w) * 1024 + (l32 >> 4) * 512 + ((l32 >> 3) & 1) * 256
          + (l32 & 7);
#pragma unroll
      for (int r = 0; r < 16; r++) {
        int rr = (r & 3) + 8 * (r >> 2) + 4 * half;
        vb[rr * 8] = __float2bfloat16(O[r] + bb[r]);
      }
    }
  }
}

// ---------------------------------------------------------------------------
// attn R13: R8 body, counted-vmcnt pipeline. Grid 512, 4 waves = (kh, chh).
// kbuf[3] triple buffer, stage distance 2; V issued before stage DMA (FIFO:
// PV's V-wait = vmcnt(4), never drains the in-flight DMA); raw s_barrier in
// main loop (no vmcnt(0) drain); __syncthreads only prologue/epilogue.
// ---------------------------------------------------------------------------
struct AttnSmem {
  union {
    __hip_bfloat16 kbuf[3][8192];   // 3 x 16 KiB triple buffer
    float ostage[256][33];          // epilogue [ch][q], pad 33
  } u;
  float redu[4][32];
  float rinv[32];
};

__global__ __launch_bounds__(256, 3) void attn_kernel(
    const __hip_bfloat16* __restrict__ qv, const __hip_bfloat16* __restrict__ kv,
    const __hip_bfloat16* __restrict__ vv,
    const float* __restrict__ x_main, const float* __restrict__ gammap,
    float* __restrict__ out)
{
  __shared__ AttnSmem sm;
  const int i  = blockIdx.x;           // 512 blocks
  const int b  = (i & 7) >> 1;         // XCD-pair -> batch (K+V L2-resident)
  const int qt = ((i >> 3) << 1) | (i & 1);
  const int n0 = qt * 32;
  const int tid  = threadIdx.x;
  const int w    = tid >> 6, lane = tid & 63, l32 = lane & 31;
  const int kh   = w >> 1, chh = w & 1;
  const int t0   = qt & 63;            // stagger: de-correlate block streams

  // Q B-fragments (coalesced frag-order)
  bf16x8 qf[8];
  {
    const __hip_bfloat16* qb = qv + ((size_t)(b * 128 + qt)) * 4096 + lane * 8;
#pragma unroll
    for (int cs = 0; cs < 8; cs++) qf[cs] = *(const bf16x8*)(qb + cs * 512);
  }

  const __hip_bfloat16* kg = kv + (size_t)(b * 128) * 4096;
  const __hip_bfloat16* vg = vv + (size_t)(b * 128) * 8192;

  auto stage = [&](int ta, int par) {
    __hip_bfloat16* kd = sm.u.kbuf[par];
    const __hip_bfloat16* ksrc = kg + (size_t)ta * 8192 + lane * 8;
#pragma unroll
    for (int c = 0; c < 4; c++) {
      int ck = w * 4 + c;
      dma16(ksrc + ck * 512, kd + ck * 512 + lane * 8);
    }
  };

  f32x16 Oacc[4];   // O^T: 128 ch (chh half) x 32 q, partial over kh keys
#pragma unroll
  for (int c = 0; c < 4; c++)
#pragma unroll
    for (int r = 0; r < 16; r++) Oacc[c][r] = 0.f;

  float l_lane = 0.f;

  // ---- prologue: stage tiles t0, t0+1; one-time full drain ----
  stage(t0, 0);
  stage((t0 + 1) & 63, 1);
  __syncthreads();                 // vmcnt(0): kbuf0/kbuf1 ready

  // ---- main loop: 1 raw barrier/tile, vmcnt never drained to 0 ----
#pragma unroll 1
  for (int lt = 0; lt < 64; ++lt) {
    const int ta = (lt + t0) & 63;

    // V frags FIRST (older than this iter's DMA in the vmcnt FIFO)
    const __hip_bfloat16* vb = vg + (size_t)(ta * 2 + kh) * 8192
                             + chh * 4096 + lane * 8;
    bf16x8 Vc[8];
#pragma unroll
    for (int c = 0; c < 4; c++) {
      Vc[2 * c]     = *(const bf16x8*)(vb + c * 1024);
      Vc[2 * c + 1] = *(const bf16x8*)(vb + c * 1024 + 512);
    }
    __builtin_amdgcn_sched_barrier(0);   // pin V-issue before DMA-issue

    if (lt < 62) stage((lt + 2 + t0) & 63, (lt + 2) % 3);

    // S^T = K Q from LDS (buffer staged 2 iters ago, completion proven)
    const __hip_bfloat16* kbase = sm.u.kbuf[lt % 3] + kh * 4096 + lane * 8;
    f32x16 S = {};
#pragma unroll
    for (int cs = 0; cs < 8; cs++) {
      bf16x8 kf = *(const bf16x8*)(kbase + cs * 512);
      S = __builtin_amdgcn_mfma_f32_32x32x16_bf16(kf, qf[cs], S, 0, 0, 0);
    }

    // P = exp2(S - 64), pack bf16 (shuffle-free via K perm)
    unsigned p2[8];
    float lsub = 0.f;
#pragma unroll
    for (int i2 = 0; i2 < 8; i2++) {
      float a = exp2f(S[2 * i2]     - 64.0f);
      float c = exp2f(S[2 * i2 + 1] - 64.0f);
      lsub += a + c;
      union { __hip_bfloat162 h; unsigned u; } cv;
      cv.h = __float22bfloat162_rn(float2{a, c});
      p2[i2] = cv.u;
    }
    l_lane += lsub;
    U4 f0, f1;
    f0.u[0] = p2[0]; f0.u[1] = p2[1]; f0.u[2] = p2[2]; f0.u[3] = p2[3];
    f1.u[0] = p2[4]; f1.u[1] = p2[5]; f1.u[2] = p2[6]; f1.u[3] = p2[7];
    const bf16x8 pf0 = f0.v, pf1 = f1.v;

    // PV: compiler's wait for Vc here is vmcnt(4) (4 newest = in-flight DMA)
#pragma unroll
    for (int c = 0; c < 4; c++) {
      Oacc[c] = __builtin_amdgcn_mfma_f32_32x32x16_bf16(Vc[2 * c],     pf0, Oacc[c], 0, 0, 0);
      Oacc[c] = __builtin_amdgcn_mfma_f32_32x32x16_bf16(Vc[2 * c + 1], pf1, Oacc[c], 0, 0, 0);
    }

    if (lt < 63) {
      __builtin_amdgcn_sched_barrier(0);     // no ds_read hoists above barrier
      __builtin_amdgcn_s_barrier();          // raw: NO vmcnt(0) drain
      __builtin_amdgcn_sched_barrier(0);     // no next-iter reads hoist above
    }
  }

  // ---- epilogue: publish l, kh-merge via ostage (ch rows), writeout ----
  float lfull = l_lane + __shfl_xor(l_lane, 32);
  if (lane < 32) sm.redu[w][l32] = lfull;
  __syncthreads();                 // full drain; kbuf reads done; redu published
  const int hb = lane >> 5;
  if (kh == 0) {
#pragma unroll
    for (int c = 0; c < 4; c++) {
#pragma unroll
      for (int r = 0; r < 16; r++) {
        int ch = (chh * 4 + c) * 32 + (r & 3) + 8 * (r >> 2) + 4 * hb;
        sm.u.ostage[ch][l32] = Oacc[c][r];
      }
    }
  }
  if (tid < 32) sm.rinv[tid] = 1.0f / (sm.redu[0][tid] + sm.redu[2][tid]);
  __syncthreads();
  if (kh == 1) {
#pragma unroll
    for (int c = 0; c < 4; c++) {
#pragma unroll
      for (int r = 0; r < 16; r++) {
        int ch = (chh * 4 + c) * 32 + (r & 3) + 8 * (r >> 2) + 4 * hb;
        sm.u.ostage[ch][l32] += Oacc[c][r];
      }
    }
  }
  __syncthreads();

  const float gmm = gammap[0];
  const int pix = tid & 31;
  const float ri = sm.rinv[pix];
#pragma unroll
  for (int j = 0; j < 32; ++j) {
    int ch = (tid >> 5) * 32 + j;
    size_t g = ((size_t)(b * 256 + ch)) * 4096 + n0 + pix;
    out[g] = gmm * sm.u.ostage[ch][pix] * ri + x_main[g];
  }
}

// ---------------------------------------------------------------------------
extern "C" void kernel_launch(void* const* d_in, const int* in_sizes, int n_in,
                              void* d_out, int out_size, void* d_ws, size_t ws_size,
                              hipStream_t stream) {
  (void)in_sizes; (void)n_in; (void)out_size; (void)ws_size;
  const float* x  = (const float*)d_in[0];
  const float* z  = (const float*)d_in[1];
  const float* Wq = (const float*)d_in[2];
  const float* bq = (const float*)d_in[3];
  const float* Wk = (const float*)d_in[4];
  const float* bk = (const float*)d_in[5];
  const float* Wv = (const float*)d_in[6];
  const float* bv = (const float*)d_in[7];
  const float* gm = (const float*)d_in[8];
  float* out = (float*)d_out;

  char* ws = (char*)d_ws;
  const size_t MB = 1024 * 1024;
  __hip_bfloat16* qp  = (__hip_bfloat16*)(ws);             // 4 MiB
  __hip_bfloat16* kp  = (__hip_bfloat16*)(ws + 4 * MB);    // 4 MiB
  __hip_bfloat16* vp  = (__hip_bfloat16*)(ws + 8 * MB);    // 8 MiB
  __hip_bfloat16* xfp = (__hip_bfloat16*)(ws + 16 * MB);   // 8 MiB
  __hip_bfloat16* zfp = (__hip_bfloat16*)(ws + 24 * MB);   // 8 MiB
  __hip_bfloat16* wfp = (__hip_bfloat16*)(ws + 32 * MB);   // 256 KiB

  prep_kernel<<<516, 256, 0, stream>>>(x, z, Wq, Wk, Wv, xfp, zfp, wfp);
  proj_mfma  <<<1024, 256, 0, stream>>>(xfp, zfp, wfp, bq, bk, bv, qp, kp, vp);
  attn_kernel<<<512, 256, 0, stream>>>(qp, kp, vp, x, gm, out);
}